// Round 4
// baseline (614.603 us; speedup 1.0000x reference)
//
#include <hip/hip_runtime.h>

typedef unsigned short u16;
typedef unsigned int u32;

#define BB 8
#define NN 4096
#define NPP 1024
#define NSS 32
#define CFF 64
#define C0 67
#define C0P 80
#define H0 64
#define H1 128
#define H2 256
#define MTOT (BB*NPP*NSS)   // 262144
#define BN_EPS 1e-5f
#define INV_M (1.0f/262144.0f)

__device__ __forceinline__ float bf2f(u16 h){ return __uint_as_float(((u32)h)<<16); }
__device__ __forceinline__ u16 f2bf(float f){
  u32 u = __float_as_uint(f);
  u32 r = (u + 0x7fffu + ((u>>16)&1u)) >> 16;
  return (u16)r;
}
__device__ __forceinline__ u32 pack2(float a, float b){
  return (u32)f2bf(a) | ((u32)f2bf(b)<<16);
}

// ---------------------------------------------------------------------------
// DTYPE CONTRACT (R3 post-mortem): inputs f32 (R2 NaN proof), indices int32,
// OUTPUT f32 (R3 error=7.0 = u16-pair misread proof; matches reference f32).
// Internal activations bf16, weights/stats f32.
//
// ws layout (bytes) — total 46,370,816 B = 44.2 MB
//   stats  [0, 49152)          : 3 x 4096 f32 (sum[8][256], sq[8][256]) per layer
//   Wt1    [49152, 81920)      : 64x128 f32 K-major
//   Wt2    [81920, 212992)     : 128x256 f32 K-major
//   Wt0    [212992, 233472)    : 80x64 f32 K-major (zero-padded K)
//   ptsT   [233472, 4427776)   : (B,N,CF) bf16
//   y0     [4427776, 37982208) : (M,64) bf16 (conv0 out, no bias: BN kills it)
//   mx     [37982208, 42176512): (B*NP,256) bf16 per-(p,c) max over NS
//   mn     [42176512, 46370816): (B*NP,256) bf16 min
// ---------------------------------------------------------------------------
#define WS_NEED 46370816u

// ---------------------------------------------------------------------------
__global__ __launch_bounds__(256) void k_setup(
    const float* __restrict__ xyz, const float* __restrict__ points,
    const int* __restrict__ sidx,
    const float* __restrict__ W0, const float* __restrict__ W1, const float* __restrict__ W2,
    u16* __restrict__ ptsT, float* __restrict__ Wt0, float* __restrict__ Wt1,
    float* __restrict__ Wt2, float* __restrict__ out_newxyz)
{
  int blk = blockIdx.x, tid = threadIdx.x;
  if (blk < 512) {
    __shared__ float t[64][65];
    int b = blk >> 6, n0 = (blk & 63) << 6;
    int nloc = tid & 63, cpart = tid >> 6;
    for (int i = 0; i < 16; ++i) {
      int c = i*4 + cpart;
      t[c][nloc] = points[(size_t)(b*CFF + c)*NN + n0 + nloc];
    }
    __syncthreads();
    int cloc = tid & 63, npart = tid >> 6;
    for (int i = 0; i < 16; ++i) {
      int n = i*4 + npart;
      ptsT[((size_t)(b*NN + n0 + n))*CFF + cloc] = f2bf(t[cloc][n]);
    }
  } else if (blk < 544) {
    int t0 = (blk - 512)*256 + tid;          // 0..8191 = b*NP + p
    int b = t0 >> 10;
    int s = sidx[t0];
    for (int k = 0; k < 3; ++k)
      out_newxyz[(size_t)t0*3 + k] = xyz[((size_t)(b*NN + s))*3 + k];   // exact f32 copy
  } else if (blk == 544) {
    for (int i = 0; i < 20; ++i) {
      int e = i*256 + tid;                   // e = k*64 + o
      int k = e >> 6, o = e & 63;
      Wt0[e] = (k < C0) ? W0[o*C0 + k] : 0.f;
    }
  } else if (blk == 545) {
    for (int i = 0; i < 32; ++i) {
      int e = i*256 + tid;                   // e = k*128 + o
      int k = e >> 7, o = e & 127;
      Wt1[e] = W1[o*H0 + k];
    }
  } else {
    int base = (blk - 546) * 4096;           // blocks 546..553
    for (int i = 0; i < 16; ++i) {
      int e = base + i*256 + tid;            // e = k*256 + o
      int k = e >> 8, o = e & 255;
      Wt2[e] = W2[o*H1 + k];
    }
  }
}

// fallback when ws too small: exact output0, zero output1 (clean diagnostic)
__global__ __launch_bounds__(256) void k_xyz_only(
    const float* __restrict__ xyz, const int* __restrict__ sidx, float* __restrict__ out_newxyz)
{
  int t0 = blockIdx.x*256 + threadIdx.x;
  int b = t0 >> 10;
  int s = sidx[t0];
  for (int k = 0; k < 3; ++k)
    out_newxyz[(size_t)t0*3 + k] = xyz[((size_t)(b*NN + s))*3 + k];
}

// ---------------------------------------------------------------------------
// L0: gather+concat -> GEMM (K=80 padded, Cout=64) -> y0 bf16 + stats0
// ---------------------------------------------------------------------------
__global__ __launch_bounds__(256) void k_l0(
    const float* __restrict__ xyz, const int* __restrict__ sidx, const int* __restrict__ nidx,
    const u16* __restrict__ ptsT, const float* __restrict__ Wt0,
    u16* __restrict__ y0, float* __restrict__ stats)
{
  __shared__ float XL[C0P*64];   // [k][pos] 20KB
  __shared__ float WL[C0P*64];   // 20KB
  int tid = threadIdx.x;
  int m0 = blockIdx.x * 64;
  int b = m0 >> 15;

  for (int i = 0; i < 20; ++i) WL[i*256 + tid] = Wt0[i*256 + tid];

  int pos = tid & 63, grp = tid >> 6;
  int m = m0 + pos;
  int nb = nidx[m];
  {
    const u16* prow = ptsT + ((size_t)(b*NN + nb))*CFF + grp*16;
    u16 hs[16];
    *(uint4*)&hs[0] = *(const uint4*)prow;
    *(uint4*)&hs[8] = *(const uint4*)(prow + 8);
    for (int j = 0; j < 16; ++j)
      XL[(3 + grp*16 + j)*64 + pos] = bf2f(hs[j]);
    if (grp == 0) {
      int p = (m & 32767) >> 5;
      int sp = sidx[b*NPP + p];
      for (int k = 0; k < 3; ++k)
        XL[k*64 + pos] = xyz[((size_t)(b*NN+nb))*3 + k] - xyz[((size_t)(b*NN+sp))*3 + k];
    } else if (grp == 1) {
      for (int k = C0; k < C0P; ++k) XL[k*64 + pos] = 0.f;
    }
  }
  __syncthreads();

  int tpos = tid & 15, tch = tid >> 4;
  float acc[4][4] = {};
  #pragma unroll 8
  for (int k = 0; k < C0P; ++k) {
    float4 x4 = *(const float4*)&XL[k*64 + tpos*4];
    float4 w4 = *(const float4*)&WL[k*64 + tch*4];
    float xv[4] = {x4.x, x4.y, x4.z, x4.w};
    float wv[4] = {w4.x, w4.y, w4.z, w4.w};
    for (int i = 0; i < 4; ++i)
      for (int j = 0; j < 4; ++j)
        acc[i][j] = fmaf(xv[i], wv[j], acc[i][j]);
  }

  float bs[4], bq[4];
  for (int j = 0; j < 4; ++j) {
    float s = 0.f, q = 0.f;
    for (int i = 0; i < 4; ++i) { float y = acc[i][j]; s += y; q += y*y; }
    bs[j] = s; bq[j] = q;
  }
  for (int msk = 1; msk < 16; msk <<= 1)
    for (int j = 0; j < 4; ++j) { bs[j] += __shfl_xor(bs[j], msk); bq[j] += __shfl_xor(bq[j], msk); }
  if (tpos == 0) {
    int slot = blockIdx.x & 7;
    for (int j = 0; j < 4; ++j) {
      atomicAdd(&stats[slot*256 + tch*4 + j], bs[j]);
      atomicAdd(&stats[2048 + slot*256 + tch*4 + j], bq[j]);
    }
  }
  for (int i = 0; i < 4; ++i) {
    int row = m0 + tpos*4 + i;
    uint2 v = { pack2(acc[i][0], acc[i][1]), pack2(acc[i][2], acc[i][3]) };
    *(uint2*)&y0[(size_t)row*H0 + tch*4] = v;
  }
}

// ---------------------------------------------------------------------------
// L1 stats pass: BN0+ReLU (from stats0) + GEMM1 -> stats1 only (y1 discarded)
// ---------------------------------------------------------------------------
__global__ __launch_bounds__(256) void k_l1s(
    const u16* __restrict__ y0, const float* __restrict__ Wt1,
    const float* __restrict__ gma, const float* __restrict__ bta,
    const float* __restrict__ stIn, float* __restrict__ stOut)
{
  __shared__ float XL[H0*64];     // 16KB
  __shared__ float WL[H0*128];    // 32KB
  __shared__ float scl[H0], sft[H0];
  int tid = threadIdx.x;
  int m0 = blockIdx.x * 64;

  if (tid < H0) {
    float s = 0.f, q = 0.f;
    for (int sl = 0; sl < 8; ++sl) { s += stIn[sl*256 + tid]; q += stIn[2048 + sl*256 + tid]; }
    float mu = s*INV_M, var = q*INV_M - mu*mu;
    float sc = gma[tid] * rsqrtf(var + BN_EPS);
    scl[tid] = sc; sft[tid] = bta[tid] - mu*sc;
  }
  for (int i = 0; i < 32; ++i) WL[i*256 + tid] = Wt1[i*256 + tid];
  __syncthreads();

  {
    int pos = tid & 63, grp = tid >> 6;
    const u16* row = y0 + (size_t)(m0 + pos)*H0 + grp*16;
    u16 hs[16];
    *(uint4*)&hs[0] = *(const uint4*)row;
    *(uint4*)&hs[8] = *(const uint4*)(row + 8);
    for (int j = 0; j < 16; ++j) {
      int c = grp*16 + j;
      XL[c*64 + pos] = fmaxf(fmaf(scl[c], bf2f(hs[j]), sft[c]), 0.f);
    }
  }
  __syncthreads();

  int tpos = tid & 15, tch = tid >> 4;
  float acc[4][8] = {};
  #pragma unroll 4
  for (int k = 0; k < H0; ++k) {
    float4 x4 = *(const float4*)&XL[k*64 + tpos*4];
    const float* wr = &WL[k*128 + tch*8];
    float4 wa = *(const float4*)wr;
    float4 wb = *(const float4*)(wr + 4);
    float xv[4] = {x4.x, x4.y, x4.z, x4.w};
    float wv[8] = {wa.x, wa.y, wa.z, wa.w, wb.x, wb.y, wb.z, wb.w};
    for (int i = 0; i < 4; ++i)
      for (int j = 0; j < 8; ++j)
        acc[i][j] = fmaf(xv[i], wv[j], acc[i][j]);
  }

  float bs[8], bq[8];
  for (int j = 0; j < 8; ++j) {
    float s = 0.f, q = 0.f;
    for (int i = 0; i < 4; ++i) { float y = acc[i][j]; s += y; q += y*y; }
    bs[j] = s; bq[j] = q;
  }
  for (int msk = 1; msk < 16; msk <<= 1)
    for (int j = 0; j < 8; ++j) { bs[j] += __shfl_xor(bs[j], msk); bq[j] += __shfl_xor(bq[j], msk); }
  if (tpos == 0) {
    int slot = blockIdx.x & 7;
    for (int j = 0; j < 8; ++j) {
      atomicAdd(&stOut[slot*256 + tch*8 + j], bs[j]);
      atomicAdd(&stOut[2048 + slot*256 + tch*8 + j], bq[j]);
    }
  }
}

// ---------------------------------------------------------------------------
// L2 fused: BN0+ReLU -> GEMM1 (recompute, identical tiling) -> BN1+ReLU (regs)
//          -> GEMM2 (W2 in 16-row LDS chunks) -> max/min over NS -> mx/mn + stats2
// ---------------------------------------------------------------------------
__global__ __launch_bounds__(256) void k_l2f(
    const u16* __restrict__ y0, const float* __restrict__ Wt1, const float* __restrict__ Wt2,
    const float* __restrict__ g0, const float* __restrict__ e0,
    const float* __restrict__ g1, const float* __restrict__ e1,
    const float* __restrict__ st0, const float* __restrict__ st1, float* __restrict__ stOut,
    u16* __restrict__ mxp, u16* __restrict__ mnp)
{
  __shared__ float X0[H0*64];     // 16KB  [k][pos]
  __shared__ float U[H1*64];      // 32KB  phase A: W1 (64x128); phase B: X1 [c][pos]
  __shared__ float W2c[16*256];   // 16KB
  __shared__ float scl0[H0], sft0[H0], scl1[H1], sft1[H1];
  int tid = threadIdx.x;
  int m0 = blockIdx.x * 64;

  if (tid < H0) {
    float s = 0.f, q = 0.f;
    for (int sl = 0; sl < 8; ++sl) { s += st0[sl*256 + tid]; q += st0[2048 + sl*256 + tid]; }
    float mu = s*INV_M, var = q*INV_M - mu*mu;
    float sc = g0[tid] * rsqrtf(var + BN_EPS);
    scl0[tid] = sc; sft0[tid] = e0[tid] - mu*sc;
  }
  if (tid < H1) {
    float s = 0.f, q = 0.f;
    for (int sl = 0; sl < 8; ++sl) { s += st1[sl*256 + tid]; q += st1[2048 + sl*256 + tid]; }
    float mu = s*INV_M, var = q*INV_M - mu*mu;
    float sc = g1[tid] * rsqrtf(var + BN_EPS);
    scl1[tid] = sc; sft1[tid] = e1[tid] - mu*sc;
  }
  for (int i = 0; i < 32; ++i) U[i*256 + tid] = Wt1[i*256 + tid];
  {
    int pos = tid & 63, grp = tid >> 6;
    const u16* row = y0 + (size_t)(m0 + pos)*H0 + grp*16;
    u16 hs[16];
    *(uint4*)&hs[0] = *(const uint4*)row;
    *(uint4*)&hs[8] = *(const uint4*)(row + 8);
    __syncthreads();   // scl0/scl1/U(W1) ready
    for (int j = 0; j < 16; ++j) {
      int c = grp*16 + j;
      X0[c*64 + pos] = fmaxf(fmaf(scl0[c], bf2f(hs[j]), sft0[c]), 0.f);
    }
  }
  __syncthreads();

  int tpos = tid & 15, tch = tid >> 4;
  // ---- GEMM1 (identical tiling/order to k_l1s) ----
  float acc1[4][8] = {};
  #pragma unroll 4
  for (int k = 0; k < H0; ++k) {
    float4 x4 = *(const float4*)&X0[k*64 + tpos*4];
    const float* wr = &U[k*128 + tch*8];
    float4 wa = *(const float4*)wr;
    float4 wb = *(const float4*)(wr + 4);
    float xv[4] = {x4.x, x4.y, x4.z, x4.w};
    float wv[8] = {wa.x, wa.y, wa.z, wa.w, wb.x, wb.y, wb.z, wb.w};
    for (int i = 0; i < 4; ++i)
      for (int j = 0; j < 8; ++j)
        acc1[i][j] = fmaf(xv[i], wv[j], acc1[i][j]);
  }
  __syncthreads();               // all reads of U (W1) done
  for (int i = 0; i < 4; ++i)
    for (int j = 0; j < 8; ++j) {
      int c = tch*8 + j, pos = tpos*4 + i;
      U[c*64 + pos] = fmaxf(fmaf(scl1[c], acc1[i][j], sft1[c]), 0.f);
    }
  __syncthreads();               // X1 ready

  // ---- GEMM2 ----
  float acc2[4][16] = {};
  for (int kc = 0; kc < 8; ++kc) {
    for (int i = 0; i < 16; ++i) W2c[i*256 + tid] = Wt2[(size_t)(kc*16 + i)*256 + tid];
    __syncthreads();
    #pragma unroll 4
    for (int kk = 0; kk < 16; ++kk) {
      int k = kc*16 + kk;
      float4 x4 = *(const float4*)&U[k*64 + tpos*4];
      const float* wr = &W2c[kk*256 + tch*16];
      float4 w0 = *(const float4*)wr,       w1 = *(const float4*)(wr + 4);
      float4 w2 = *(const float4*)(wr + 8), w3 = *(const float4*)(wr + 12);
      float xv[4] = {x4.x, x4.y, x4.z, x4.w};
      float wv[16] = {w0.x,w0.y,w0.z,w0.w, w1.x,w1.y,w1.z,w1.w,
                      w2.x,w2.y,w2.z,w2.w, w3.x,w3.y,w3.z,w3.w};
      for (int i = 0; i < 4; ++i)
        for (int j = 0; j < 16; ++j)
          acc2[i][j] = fmaf(xv[i], wv[j], acc2[i][j]);
    }
    __syncthreads();
  }

  // ---- stats2 ----
  {
    float bs[16], bq[16];
    for (int j = 0; j < 16; ++j) {
      float s = 0.f, q = 0.f;
      for (int i = 0; i < 4; ++i) { float y = acc2[i][j]; s += y; q += y*y; }
      bs[j] = s; bq[j] = q;
    }
    for (int msk = 1; msk < 16; msk <<= 1)
      for (int j = 0; j < 16; ++j) { bs[j] += __shfl_xor(bs[j], msk); bq[j] += __shfl_xor(bq[j], msk); }
    if (tpos == 0) {
      int slot = blockIdx.x & 7;
      for (int j = 0; j < 16; ++j) {
        atomicAdd(&stOut[slot*256 + tch*16 + j], bs[j]);
        atomicAdd(&stOut[2048 + slot*256 + tch*16 + j], bq[j]);
      }
    }
  }

  // ---- max/min over NS (pos groups of 32) ----
  {
    float mx[16], mn[16];
    for (int j = 0; j < 16; ++j) {
      mx[j] = fmaxf(fmaxf(acc2[0][j], acc2[1][j]), fmaxf(acc2[2][j], acc2[3][j]));
      mn[j] = fminf(fminf(acc2[0][j], acc2[1][j]), fminf(acc2[2][j], acc2[3][j]));
    }
    for (int msk = 1; msk <= 4; msk <<= 1)
      for (int j = 0; j < 16; ++j) {
        mx[j] = fmaxf(mx[j], __shfl_xor(mx[j], msk));
        mn[j] = fminf(mn[j], __shfl_xor(mn[j], msk));
      }
    if ((tid & 7) == 0) {
      int prow = m0/32 + ((tid >> 3) & 1);     // global b*NP+p
      size_t base = (size_t)prow*H2 + tch*16;
      uint4 a = { pack2(mx[0],mx[1]), pack2(mx[2],mx[3]), pack2(mx[4],mx[5]), pack2(mx[6],mx[7]) };
      uint4 b = { pack2(mx[8],mx[9]), pack2(mx[10],mx[11]), pack2(mx[12],mx[13]), pack2(mx[14],mx[15]) };
      *(uint4*)&mxp[base] = a;  *(uint4*)&mxp[base + 8] = b;
      uint4 c = { pack2(mn[0],mn[1]), pack2(mn[2],mn[3]), pack2(mn[4],mn[5]), pack2(mn[6],mn[7]) };
      uint4 d = { pack2(mn[8],mn[9]), pack2(mn[10],mn[11]), pack2(mn[12],mn[13]), pack2(mn[14],mn[15]) };
      *(uint4*)&mnp[base] = c;  *(uint4*)&mnp[base + 8] = d;
    }
  }
}

// ---------------------------------------------------------------------------
// Final: BN2 on mx/mn + ReLU -> new_points (B,256,NP) FLOAT32, LDS transpose
// ---------------------------------------------------------------------------
__global__ __launch_bounds__(256) void k_final(
    const u16* __restrict__ mxp, const u16* __restrict__ mnp,
    const float* __restrict__ gma, const float* __restrict__ bta,
    const float* __restrict__ stIn, float* __restrict__ out_np)
{
  __shared__ float tmp[256][33];  // 33.8KB
  int tid = threadIdx.x;
  int b = blockIdx.x >> 5;
  int p0 = (blockIdx.x & 31) * 32;

  float s = 0.f, q = 0.f;
  for (int sl = 0; sl < 8; ++sl) { s += stIn[sl*256 + tid]; q += stIn[2048 + sl*256 + tid]; }
  float mu = s*INV_M, var = q*INV_M - mu*mu;
  float sc = gma[tid] * rsqrtf(var + BN_EPS);
  float sh = bta[tid] - mu*sc;

  for (int pp = 0; pp < 32; ++pp) {
    size_t base = ((size_t)(b*NPP + p0 + pp))*H2 + tid;
    float xv = bf2f(mxp[base]), nv = bf2f(mnp[base]);
    float v = (sc >= 0.f) ? fmaf(sc, xv, sh) : fmaf(sc, nv, sh);
    tmp[tid][pp] = fmaxf(v, 0.f);
  }
  __syncthreads();

  int pl = tid & 31, cg = tid >> 5;
  for (int cc = 0; cc < 32; ++cc) {
    int c = cc*8 + cg;
    out_np[((size_t)b*H2 + c)*NPP + p0 + pl] = tmp[c][pl];
  }
}

// ---------------------------------------------------------------------------
extern "C" void kernel_launch(void* const* d_in, const int* in_sizes, int n_in,
                              void* d_out, int out_size, void* d_ws, size_t ws_size,
                              hipStream_t stream)
{
  const float* xyz    = (const float*)d_in[0];
  const float* points = (const float*)d_in[1];
  const int*   sidx   = (const int*)d_in[2];
  const int*   nidx   = (const int*)d_in[3];
  const float* W0 = (const float*)d_in[4];
  const float* g0 = (const float*)d_in[6];
  const float* e0 = (const float*)d_in[7];
  const float* W1 = (const float*)d_in[8];
  const float* g1 = (const float*)d_in[10];
  const float* e1 = (const float*)d_in[11];
  const float* W2 = (const float*)d_in[12];
  const float* g2 = (const float*)d_in[14];
  const float* e2 = (const float*)d_in[15];

  float* out_xyz = (float*)d_out;                       // (B,NP,3) f32
  float* out_np  = out_xyz + (size_t)BB*NPP*3;          // (B,256,NP) f32

  if (ws_size < (size_t)WS_NEED) {
    hipMemsetAsync(out_np, 0, (size_t)BB*H2*NPP*4, stream);
    k_xyz_only<<<32, 256, 0, stream>>>(xyz, sidx, out_xyz);
    return;
  }

  char* ws = (char*)d_ws;
  float* stats = (float*)(ws + 0);
  float* Wt1   = (float*)(ws + 49152);
  float* Wt2   = (float*)(ws + 81920);
  float* Wt0   = (float*)(ws + 212992);
  u16*   ptsT  = (u16*)  (ws + 233472);
  u16*   y0    = (u16*)  (ws + 4427776);
  u16*   mxp   = (u16*)  (ws + 37982208);
  u16*   mnp   = (u16*)  (ws + 42176512);

  hipMemsetAsync(stats, 0, 3*4096*sizeof(float), stream);
  k_setup<<<554, 256, 0, stream>>>(xyz, points, sidx, W0, W1, W2,
                                   ptsT, Wt0, Wt1, Wt2, out_xyz);
  k_l0<<<MTOT/64, 256, 0, stream>>>(xyz, sidx, nidx, ptsT, Wt0, y0, stats);
  k_l1s<<<MTOT/64, 256, 0, stream>>>(y0, Wt1, g0, e0, stats, stats + 4096);
  k_l2f<<<MTOT/64, 256, 0, stream>>>(y0, Wt1, Wt2, g0, e0, g1, e1,
                                     stats, stats + 4096, stats + 8192, mxp, mnp);
  k_final<<<256, 256, 0, stream>>>(mxp, mnp, g2, e2, stats + 8192, out_np);
}

// Round 5
// 184.000 us; speedup vs baseline: 3.3402x; 3.3402x over previous
//
#include <hip/hip_runtime.h>

typedef unsigned short u16;
typedef unsigned int u32;
typedef __attribute__((ext_vector_type(8))) short short8;   // 8 bf16 (4 VGPRs)
typedef __attribute__((ext_vector_type(4))) float f32x4;

#define BB 8
#define NN 4096
#define NPP 1024
#define NSS 32
#define CFF 64
#define C0 67
#define H0 64
#define H1 128
#define H2 256
#define MTOT (BB*NPP*NSS)   // 262144
#define BN_EPS 1e-5f
#define INV_M (1.0f/262144.0f)

#define MFMA16(a,b,c) __builtin_amdgcn_mfma_f32_16x16x32_bf16(a,b,c,0,0,0)

__device__ __forceinline__ float bf2f(u16 h){ return __uint_as_float(((u32)h)<<16); }
__device__ __forceinline__ u16 f2bf(float f){
  u32 u = __float_as_uint(f);
  u32 r = (u + 0x7fffu + ((u>>16)&1u)) >> 16;
  return (u16)r;
}
__device__ __forceinline__ u32 pack2(float a, float b){
  return (u32)f2bf(a) | ((u32)f2bf(b)<<16);
}

// ---------------------------------------------------------------------------
// All MFMA operands use chunked-K LDS/global layout: [k/8][row][8 bf16].
// Fragment reads are one aligned ds_read_b128; lanes 0..15 read consecutive
// 16B rows -> conflict-free.
//
// X channel permutation for L0 (chunk-aligns the gathered features):
//   X[k]=feat[k] (k<64), X[64..66]=rel xyz, X[67..95]=0 ; Wt0c permuted to match.
//
// ws layout (bytes), total 46,280,704:
//   stats [0,49152)           3 x 4096 f32
//   Wt0c  [49152,61440)       [12][64][8] bf16
//   Wt1c  [61440,77824)       [8][128][8] bf16
//   Wt2c  [77824,143360)      [16][256][8] bf16
//   ptsT  [143360,4337664)    (B,N,64) bf16
//   y0    [4337664,37892096)  (M,64) bf16
//   mxp   [37892096,42086400) (B*NP,256) bf16
//   mnp   [42086400,46280704) (B*NP,256) bf16
// ---------------------------------------------------------------------------
#define WS_NEED 46280704u

__global__ __launch_bounds__(256) void k_setup(
    const float* __restrict__ xyz, const float* __restrict__ points,
    const int* __restrict__ sidx,
    const float* __restrict__ W0, const float* __restrict__ W1, const float* __restrict__ W2,
    u16* __restrict__ ptsT, u16* __restrict__ Wt0c, u16* __restrict__ Wt1c,
    u16* __restrict__ Wt2c, float* __restrict__ out_newxyz)
{
  int blk = blockIdx.x, tid = threadIdx.x;
  if (blk < 512) {
    __shared__ float t[64][65];
    int b = blk >> 6, n0 = (blk & 63) << 6;
    int nloc = tid & 63, cpart = tid >> 6;
    for (int i = 0; i < 16; ++i) {
      int c = i*4 + cpart;
      t[c][nloc] = points[(size_t)(b*CFF + c)*NN + n0 + nloc];
    }
    __syncthreads();
    int cloc = tid & 63, npart = tid >> 6;
    for (int i = 0; i < 16; ++i) {
      int n = i*4 + npart;
      ptsT[((size_t)(b*NN + n0 + n))*CFF + cloc] = f2bf(t[cloc][n]);
    }
  } else if (blk < 544) {
    int t0 = (blk - 512)*256 + tid;
    int b = t0 >> 10;
    int s = sidx[t0];
    for (int k = 0; k < 3; ++k)
      out_newxyz[(size_t)t0*3 + k] = xyz[((size_t)(b*NN + s))*3 + k];
  } else if (blk == 544) {
    for (int i = 0; i < 24; ++i) {
      int e = i*256 + tid;                 // [12 kc][64 o][8 j]
      int kc = e >> 9, o = (e >> 3) & 63, j = e & 7, k = kc*8 + j;
      float v = (k < 64) ? W0[o*C0 + 3 + k] : ((k < 67) ? W0[o*C0 + (k - 64)] : 0.f);
      Wt0c[e] = f2bf(v);
    }
  } else if (blk == 545) {
    for (int i = 0; i < 32; ++i) {
      int e = i*256 + tid;                 // [8 kc][128 n][8 j]
      int kc = e >> 10, n = (e >> 3) & 127, j = e & 7;
      Wt1c[e] = f2bf(W1[n*H0 + kc*8 + j]);
    }
  } else {
    int base = (blk - 546) * 4096;         // blocks 546..553
    for (int i = 0; i < 16; ++i) {
      int e = base + i*256 + tid;          // [16 kc][256 n][8 j]
      int kc = e >> 11, n = (e >> 3) & 255, j = e & 7;
      Wt2c[e] = f2bf(W2[n*H1 + kc*8 + j]);
    }
  }
}

__global__ __launch_bounds__(256) void k_xyz_only(
    const float* __restrict__ xyz, const int* __restrict__ sidx, float* __restrict__ out_newxyz)
{
  int t0 = blockIdx.x*256 + threadIdx.x;
  int b = t0 >> 10;
  int s = sidx[t0];
  for (int k = 0; k < 3; ++k)
    out_newxyz[(size_t)t0*3 + k] = xyz[((size_t)(b*NN + s))*3 + k];
}

// ---------------------------------------------------------------------------
// L0 (MFMA): gather+concat (chunked bf16) -> GEMM K=96 -> y0 + stats0
// ---------------------------------------------------------------------------
__global__ __launch_bounds__(256) void k_l0(
    const float* __restrict__ xyz, const int* __restrict__ sidx, const int* __restrict__ nidx,
    const u16* __restrict__ ptsT, const u16* __restrict__ Wt0c,
    u16* __restrict__ y0, float* __restrict__ stats)
{
  __shared__ u16 XLc[12*512];   // [12 kc][64 pos][8] 12 KB
  __shared__ u16 W0c[12*512];   // 12 KB
  int tid = threadIdx.x;
  int m0 = blockIdx.x * 64;
  int b = m0 >> 15;

  for (int i = 0; i < 3; ++i)
    ((uint4*)W0c)[i*256 + tid] = ((const uint4*)Wt0c)[i*256 + tid];

  int pos = tid & 63, grp = tid >> 6;
  int m = m0 + pos;
  int nb = nidx[m];
  {
    const u16* prow = ptsT + ((size_t)(b*NN + nb))*CFF + grp*16;
    uint4 h0 = *(const uint4*)prow;
    uint4 h1 = *(const uint4*)(prow + 8);
    *(uint4*)&XLc[(2*grp)*512 + pos*8]   = h0;
    *(uint4*)&XLc[(2*grp+1)*512 + pos*8] = h1;
    if (grp == 0) {
      int p = (m & 32767) >> 5;
      int sp = sidx[b*NPP + p];
      float r0 = xyz[((size_t)(b*NN+nb))*3+0] - xyz[((size_t)(b*NN+sp))*3+0];
      float r1 = xyz[((size_t)(b*NN+nb))*3+1] - xyz[((size_t)(b*NN+sp))*3+1];
      float r2 = xyz[((size_t)(b*NN+nb))*3+2] - xyz[((size_t)(b*NN+sp))*3+2];
      uint4 v = { pack2(r0, r1), pack2(r2, 0.f), 0u, 0u };
      *(uint4*)&XLc[8*512 + pos*8] = v;      // channels 64..71
    } else {
      uint4 z = {0u,0u,0u,0u};
      *(uint4*)&XLc[(8+grp)*512 + pos*8] = z; // channels 72..95 zero
    }
  }
  __syncthreads();

  int lane = tid & 63, wv = tid >> 6;
  int quad = lane >> 4, l15 = lane & 15;
  f32x4 acc0[4];
  for (int mi = 0; mi < 4; ++mi) acc0[mi] = (f32x4){0.f,0.f,0.f,0.f};

  for (int kc = 0; kc < 3; ++kc) {
    int cb = kc*4 + quad;
    short8 bfrag = *(const short8*)&W0c[(cb*64 + wv*16 + l15)*8];
    for (int mi = 0; mi < 4; ++mi) {
      short8 afrag = *(const short8*)&XLc[(cb*64 + mi*16 + l15)*8];
      acc0[mi] = MFMA16(afrag, bfrag, acc0[mi]);
    }
  }

  float s = 0.f, q = 0.f;
  for (int mi = 0; mi < 4; ++mi)
    for (int r = 0; r < 4; ++r) { float y = acc0[mi][r]; s += y; q += y*y; }
  s += __shfl_xor(s, 16); s += __shfl_xor(s, 32);
  q += __shfl_xor(q, 16); q += __shfl_xor(q, 32);
  if (lane < 16) {
    int slot = blockIdx.x & 7;
    atomicAdd(&stats[slot*256 + wv*16 + lane], s);
    atomicAdd(&stats[2048 + slot*256 + wv*16 + lane], q);
  }
  for (int mi = 0; mi < 4; ++mi)
    for (int r = 0; r < 4; ++r) {
      int row = m0 + mi*16 + quad*4 + r;
      y0[(size_t)row*H0 + wv*16 + l15] = f2bf(acc0[mi][r]);
    }
}

// ---------------------------------------------------------------------------
// L1 stats (MFMA): BN0+ReLU -> GEMM1 -> stats1 only
// ---------------------------------------------------------------------------
__global__ __launch_bounds__(256) void k_l1s(
    const u16* __restrict__ y0, const u16* __restrict__ Wt1c,
    const float* __restrict__ g0, const float* __restrict__ e0,
    const float* __restrict__ stIn, float* __restrict__ stOut)
{
  __shared__ u16 X0c[8*512];    // 8 KB [8 kc][64][8]
  __shared__ u16 W1c[8*1024];   // 16 KB [8 kc][128][8]
  __shared__ float scl0[64], sft0[64];
  int tid = threadIdx.x;
  int m0 = blockIdx.x * 64;

  if (tid < 64) {
    float s = 0.f, q = 0.f;
    for (int sl = 0; sl < 8; ++sl) { s += stIn[sl*256 + tid]; q += stIn[2048 + sl*256 + tid]; }
    float mu = s*INV_M, var = q*INV_M - mu*mu;
    float sc = g0[tid] * rsqrtf(var + BN_EPS);
    scl0[tid] = sc; sft0[tid] = e0[tid] - mu*sc;
  }
  for (int i = 0; i < 4; ++i)
    ((uint4*)W1c)[i*256 + tid] = ((const uint4*)Wt1c)[i*256 + tid];

  int pos = tid & 63, grp = tid >> 6;
  {
    const u16* row = y0 + (size_t)(m0 + pos)*H0 + grp*16;
    u16 hs[16];
    *(uint4*)&hs[0] = *(const uint4*)row;
    *(uint4*)&hs[8] = *(const uint4*)(row + 8);
    __syncthreads();     // scl0 ready
    u16 ob[16];
    for (int j = 0; j < 16; ++j) {
      int c = grp*16 + j;
      ob[j] = f2bf(fmaxf(fmaf(scl0[c], bf2f(hs[j]), sft0[c]), 0.f));
    }
    *(uint4*)&X0c[(2*grp)*512 + pos*8]   = *(uint4*)&ob[0];
    *(uint4*)&X0c[(2*grp+1)*512 + pos*8] = *(uint4*)&ob[8];
  }
  __syncthreads();

  int lane = tid & 63, wv = tid >> 6, quad = lane >> 4, l15 = lane & 15;
  f32x4 acc1[2][4];
  for (int ni = 0; ni < 2; ++ni) for (int mi = 0; mi < 4; ++mi) acc1[ni][mi] = (f32x4){0.f,0.f,0.f,0.f};

  for (int kc = 0; kc < 2; ++kc) {
    int cb = kc*4 + quad;
    short8 a[4], bfr[2];
    for (int mi = 0; mi < 4; ++mi) a[mi] = *(const short8*)&X0c[(cb*64 + mi*16 + l15)*8];
    for (int ni = 0; ni < 2; ++ni) bfr[ni] = *(const short8*)&W1c[(cb*128 + wv*32 + ni*16 + l15)*8];
    for (int ni = 0; ni < 2; ++ni)
      for (int mi = 0; mi < 4; ++mi)
        acc1[ni][mi] = MFMA16(a[mi], bfr[ni], acc1[ni][mi]);
  }

  int slot = blockIdx.x & 7;
  for (int ni = 0; ni < 2; ++ni) {
    float s = 0.f, q = 0.f;
    for (int mi = 0; mi < 4; ++mi)
      for (int r = 0; r < 4; ++r) { float y = acc1[ni][mi][r]; s += y; q += y*y; }
    s += __shfl_xor(s, 16); s += __shfl_xor(s, 32);
    q += __shfl_xor(q, 16); q += __shfl_xor(q, 32);
    if (lane < 16) {
      atomicAdd(&stOut[slot*256 + wv*32 + ni*16 + lane], s);
      atomicAdd(&stOut[2048 + slot*256 + wv*32 + ni*16 + lane], q);
    }
  }
}

// ---------------------------------------------------------------------------
// L2 fused (MFMA): GEMM1 recompute -> BN1+ReLU -> LDS (C->A layout) -> GEMM2
//                 -> stats2 + max/min over NS
// ---------------------------------------------------------------------------
__global__ __launch_bounds__(256) void k_l2f(
    const u16* __restrict__ y0, const u16* __restrict__ Wt1c, const u16* __restrict__ Wt2c,
    const float* __restrict__ g0, const float* __restrict__ e0,
    const float* __restrict__ g1, const float* __restrict__ e1,
    const float* __restrict__ st0, const float* __restrict__ st1, float* __restrict__ stOut,
    u16* __restrict__ mxp, u16* __restrict__ mnp)
{
  __shared__ u16 X1c[16*512];    // 16 KB [16 kc][64][8]
  __shared__ u16 UB[16*1024];    // 32 KB union: ph1 X0c[0..4096)+W1c[4096..12288); ph2 W2 half
  __shared__ float scl0[64], sft0[64], scl1[128], sft1[128];
  int tid = threadIdx.x;
  int m0 = blockIdx.x * 64;

  if (tid < 64) {
    float s = 0.f, q = 0.f;
    for (int sl = 0; sl < 8; ++sl) { s += st0[sl*256 + tid]; q += st0[2048 + sl*256 + tid]; }
    float mu = s*INV_M, var = q*INV_M - mu*mu;
    float sc = g0[tid] * rsqrtf(var + BN_EPS);
    scl0[tid] = sc; sft0[tid] = e0[tid] - mu*sc;
  }
  if (tid < 128) {
    float s = 0.f, q = 0.f;
    for (int sl = 0; sl < 8; ++sl) { s += st1[sl*256 + tid]; q += st1[2048 + sl*256 + tid]; }
    float mu = s*INV_M, var = q*INV_M - mu*mu;
    float sc = g1[tid] * rsqrtf(var + BN_EPS);
    scl1[tid] = sc; sft1[tid] = e1[tid] - mu*sc;
  }
  u16* X0c = UB;
  u16* W1c = UB + 4096;
  for (int i = 0; i < 4; ++i)
    ((uint4*)W1c)[i*256 + tid] = ((const uint4*)Wt1c)[i*256 + tid];

  int pos = tid & 63, grp = tid >> 6;
  {
    const u16* row = y0 + (size_t)(m0 + pos)*H0 + grp*16;
    u16 hs[16];
    *(uint4*)&hs[0] = *(const uint4*)row;
    *(uint4*)&hs[8] = *(const uint4*)(row + 8);
    __syncthreads();     // scl ready
    u16 ob[16];
    for (int j = 0; j < 16; ++j) {
      int c = grp*16 + j;
      ob[j] = f2bf(fmaxf(fmaf(scl0[c], bf2f(hs[j]), sft0[c]), 0.f));
    }
    *(uint4*)&X0c[(2*grp)*512 + pos*8]   = *(uint4*)&ob[0];
    *(uint4*)&X0c[(2*grp+1)*512 + pos*8] = *(uint4*)&ob[8];
  }
  __syncthreads();

  int lane = tid & 63, wv = tid >> 6, quad = lane >> 4, l15 = lane & 15;
  f32x4 acc1[2][4];
  for (int ni = 0; ni < 2; ++ni) for (int mi = 0; mi < 4; ++mi) acc1[ni][mi] = (f32x4){0.f,0.f,0.f,0.f};

  for (int kc = 0; kc < 2; ++kc) {
    int cb = kc*4 + quad;
    short8 a[4], bfr[2];
    for (int mi = 0; mi < 4; ++mi) a[mi] = *(const short8*)&X0c[(cb*64 + mi*16 + l15)*8];
    for (int ni = 0; ni < 2; ++ni) bfr[ni] = *(const short8*)&W1c[(cb*128 + wv*32 + ni*16 + l15)*8];
    for (int ni = 0; ni < 2; ++ni)
      for (int mi = 0; mi < 4; ++mi)
        acc1[ni][mi] = MFMA16(a[mi], bfr[ni], acc1[ni][mi]);
  }
  __syncthreads();   // all UB (X0c/W1c) reads done

  // BN1+ReLU, scatter C-layout -> A-layout (chunked) in X1c
  for (int ni = 0; ni < 2; ++ni)
    for (int mi = 0; mi < 4; ++mi)
      for (int r = 0; r < 4; ++r) {
        int ch = wv*32 + ni*16 + l15;
        int mm = mi*16 + quad*4 + r;
        float v = fmaxf(fmaf(scl1[ch], acc1[ni][mi][r], sft1[ch]), 0.f);
        X1c[(ch >> 3)*512 + mm*8 + (ch & 7)] = f2bf(v);
      }

  f32x4 acc2[4][4];
  for (int ni = 0; ni < 4; ++ni) for (int mi = 0; mi < 4; ++mi) acc2[ni][mi] = (f32x4){0.f,0.f,0.f,0.f};

  for (int h = 0; h < 2; ++h) {
    for (int i = 0; i < 8; ++i)
      ((uint4*)UB)[i*256 + tid] = ((const uint4*)(Wt2c + h*16384))[i*256 + tid];
    __syncthreads();   // W2 half staged; X1c writes visible (h=0)
    for (int kc = 0; kc < 2; ++kc) {
      int cb = kc*4 + quad;          // chunk within half (UB)
      int cx = h*8 + cb;             // chunk within X1c
      short8 a[4], bfr[4];
      for (int mi = 0; mi < 4; ++mi) a[mi] = *(const short8*)&X1c[(cx*64 + mi*16 + l15)*8];
      for (int ni = 0; ni < 4; ++ni) bfr[ni] = *(const short8*)&UB[(cb*256 + wv*64 + ni*16 + l15)*8];
      for (int ni = 0; ni < 4; ++ni)
        for (int mi = 0; mi < 4; ++mi)
          acc2[ni][mi] = MFMA16(a[mi], bfr[ni], acc2[ni][mi]);
    }
    __syncthreads();   // UB reads done before next half overwrite
  }

  // stats2 + max/min over NS (block = 2 p-groups: rows 0..31, 32..63)
  int slot = blockIdx.x & 7;
  for (int ni = 0; ni < 4; ++ni) {
    float s = 0.f, q = 0.f;
    float mx0 = -1e30f, mn0 = 1e30f, mx1 = -1e30f, mn1 = 1e30f;
    for (int mi = 0; mi < 4; ++mi)
      for (int r = 0; r < 4; ++r) {
        float y = acc2[ni][mi][r];
        s += y; q += y*y;
        if (mi < 2) { mx0 = fmaxf(mx0, y); mn0 = fminf(mn0, y); }
        else        { mx1 = fmaxf(mx1, y); mn1 = fminf(mn1, y); }
      }
    s += __shfl_xor(s, 16); s += __shfl_xor(s, 32);
    q += __shfl_xor(q, 16); q += __shfl_xor(q, 32);
    mx0 = fmaxf(mx0, __shfl_xor(mx0, 16)); mx0 = fmaxf(mx0, __shfl_xor(mx0, 32));
    mn0 = fminf(mn0, __shfl_xor(mn0, 16)); mn0 = fminf(mn0, __shfl_xor(mn0, 32));
    mx1 = fmaxf(mx1, __shfl_xor(mx1, 16)); mx1 = fmaxf(mx1, __shfl_xor(mx1, 32));
    mn1 = fminf(mn1, __shfl_xor(mn1, 16)); mn1 = fminf(mn1, __shfl_xor(mn1, 32));
    if (lane < 16) {
      int c = wv*64 + ni*16 + lane;
      atomicAdd(&stOut[slot*256 + c], s);
      atomicAdd(&stOut[2048 + slot*256 + c], q);
      size_t pr0 = (size_t)blockIdx.x*2, pr1 = pr0 + 1;
      mxp[pr0*H2 + c] = f2bf(mx0);
      mnp[pr0*H2 + c] = f2bf(mn0);
      mxp[pr1*H2 + c] = f2bf(mx1);
      mnp[pr1*H2 + c] = f2bf(mn1);
    }
  }
}

// ---------------------------------------------------------------------------
// Final: BN2 on mx/mn + ReLU -> new_points (B,256,NP) f32
// ---------------------------------------------------------------------------
__global__ __launch_bounds__(256) void k_final(
    const u16* __restrict__ mxp, const u16* __restrict__ mnp,
    const float* __restrict__ gma, const float* __restrict__ bta,
    const float* __restrict__ stIn, float* __restrict__ out_np)
{
  __shared__ float tmp[256][33];
  int tid = threadIdx.x;
  int b = blockIdx.x >> 5;
  int p0 = (blockIdx.x & 31) * 32;

  float s = 0.f, q = 0.f;
  for (int sl = 0; sl < 8; ++sl) { s += stIn[sl*256 + tid]; q += stIn[2048 + sl*256 + tid]; }
  float mu = s*INV_M, var = q*INV_M - mu*mu;
  float sc = gma[tid] * rsqrtf(var + BN_EPS);
  float sh = bta[tid] - mu*sc;

  for (int pp = 0; pp < 32; ++pp) {
    size_t base = ((size_t)(b*NPP + p0 + pp))*H2 + tid;
    float xv = bf2f(mxp[base]), nv = bf2f(mnp[base]);
    float v = (sc >= 0.f) ? fmaf(sc, xv, sh) : fmaf(sc, nv, sh);
    tmp[tid][pp] = fmaxf(v, 0.f);
  }
  __syncthreads();

  int pl = tid & 31, cg = tid >> 5;
  for (int cc = 0; cc < 32; ++cc) {
    int c = cc*8 + cg;
    out_np[((size_t)b*H2 + c)*NPP + p0 + pl] = tmp[c][pl];
  }
}

// ---------------------------------------------------------------------------
extern "C" void kernel_launch(void* const* d_in, const int* in_sizes, int n_in,
                              void* d_out, int out_size, void* d_ws, size_t ws_size,
                              hipStream_t stream)
{
  const float* xyz    = (const float*)d_in[0];
  const float* points = (const float*)d_in[1];
  const int*   sidx   = (const int*)d_in[2];
  const int*   nidx   = (const int*)d_in[3];
  const float* W0 = (const float*)d_in[4];
  const float* g0 = (const float*)d_in[6];
  const float* e0 = (const float*)d_in[7];
  const float* W1 = (const float*)d_in[8];
  const float* g1 = (const float*)d_in[10];
  const float* e1 = (const float*)d_in[11];
  const float* W2 = (const float*)d_in[12];
  const float* g2 = (const float*)d_in[14];
  const float* e2 = (const float*)d_in[15];

  float* out_xyz = (float*)d_out;
  float* out_np  = out_xyz + (size_t)BB*NPP*3;

  if (ws_size < (size_t)WS_NEED) {
    hipMemsetAsync(out_np, 0, (size_t)BB*H2*NPP*4, stream);
    k_xyz_only<<<32, 256, 0, stream>>>(xyz, sidx, out_xyz);
    return;
  }

  char* ws = (char*)d_ws;
  float* stats = (float*)(ws + 0);
  u16*   Wt0c  = (u16*)(ws + 49152);
  u16*   Wt1c  = (u16*)(ws + 61440);
  u16*   Wt2c  = (u16*)(ws + 77824);
  u16*   ptsT  = (u16*)(ws + 143360);
  u16*   y0    = (u16*)(ws + 4337664);
  u16*   mxp   = (u16*)(ws + 37892096);
  u16*   mnp   = (u16*)(ws + 42086400);

  hipMemsetAsync(stats, 0, 3*4096*sizeof(float), stream);
  k_setup<<<554, 256, 0, stream>>>(xyz, points, sidx, W0, W1, W2,
                                   ptsT, Wt0c, Wt1c, Wt2c, out_xyz);
  k_l0<<<MTOT/64, 256, 0, stream>>>(xyz, sidx, nidx, ptsT, Wt0c, y0, stats);
  k_l1s<<<MTOT/64, 256, 0, stream>>>(y0, Wt1c, g0, e0, stats, stats + 4096);
  k_l2f<<<MTOT/64, 256, 0, stream>>>(y0, Wt1c, Wt2c, g0, e0, g1, e1,
                                     stats, stats + 4096, stats + 8192, mxp, mnp);
  k_final<<<256, 256, 0, stream>>>(mxp, mnp, g2, e2, stats + 8192, out_np);
}

// Round 6
// 178.557 us; speedup vs baseline: 3.4421x; 1.0305x over previous
//
#include <hip/hip_runtime.h>

typedef unsigned short u16;
typedef unsigned int u32;
typedef __attribute__((ext_vector_type(8))) short short8;    // 8 bf16
typedef __attribute__((ext_vector_type(16))) float f32x16;

#define BB 8
#define NN 4096
#define NPP 1024
#define NSS 32
#define CFF 64
#define C0 67
#define H0 64
#define H1 128
#define H2 256
#define MTOT (BB*NPP*NSS)   // 262144
#define BN_EPS 1e-5f
#define INV_M (1.0f/262144.0f)

#define MFMA32(a,b,c) __builtin_amdgcn_mfma_f32_32x32x16_bf16(a,b,c,0,0,0)

__device__ __forceinline__ float bf2f(u16 h){ return __uint_as_float(((u32)h)<<16); }
__device__ __forceinline__ u16 f2bf(float f){
  u32 u = __float_as_uint(f);
  u32 r = (u + 0x7fffu + ((u>>16)&1u)) >> 16;
  return (u16)r;
}
__device__ __forceinline__ u32 pack2(float a, float b){
  return (u32)f2bf(a) | ((u32)f2bf(b)<<16);
}

// ---------------------------------------------------------------------------
// Chunked-K layout everywhere: [k/8][row][8 bf16]; every MFMA fragment is one
// aligned ds_read_b128. 32x32x16 MFMA: A[m=lane&31][k=(lane>>5)*8+j] (k-perm
// consistent across A/B => exact), C/D col=lane&31, row=(reg&3)+8*(reg>>2)+4*(lane>>5).
//
// ws layout (bytes), total 46,280,704 (unchanged from R5):
//   stats [0,49152) | Wt0c [49152,61440) [12][64][8] | Wt1c [61440,77824) [8][128][8]
//   Wt2c [77824,143360) [16][256][8] | ptsT [143360,4337664) (B,N,64) bf16
//   y0 [4337664,37892096) (M,64) bf16 | mxp [37892096,42086400) | mnp [42086400,46280704)
// ---------------------------------------------------------------------------
#define WS_NEED 46280704u

__global__ __launch_bounds__(256) void k_setup(
    const float* __restrict__ xyz, const float* __restrict__ points,
    const int* __restrict__ sidx,
    const float* __restrict__ W0, const float* __restrict__ W1, const float* __restrict__ W2,
    u16* __restrict__ ptsT, u16* __restrict__ Wt0c, u16* __restrict__ Wt1c,
    u16* __restrict__ Wt2c, float* __restrict__ out_newxyz)
{
  int blk = blockIdx.x, tid = threadIdx.x;
  if (blk < 512) {
    __shared__ float t[64][65];
    int b = blk >> 6, n0 = (blk & 63) << 6;
    int nloc = tid & 63, cpart = tid >> 6;
    for (int i = 0; i < 16; ++i) {
      int c = i*4 + cpart;
      t[c][nloc] = points[(size_t)(b*CFF + c)*NN + n0 + nloc];
    }
    __syncthreads();
    int cloc = tid & 63, npart = tid >> 6;
    for (int i = 0; i < 16; ++i) {
      int n = i*4 + npart;
      ptsT[((size_t)(b*NN + n0 + n))*CFF + cloc] = f2bf(t[cloc][n]);
    }
  } else if (blk < 544) {
    int t0 = (blk - 512)*256 + tid;
    int b = t0 >> 10;
    int s = sidx[t0];
    for (int k = 0; k < 3; ++k)
      out_newxyz[(size_t)t0*3 + k] = xyz[((size_t)(b*NN + s))*3 + k];
  } else if (blk == 544) {
    for (int i = 0; i < 24; ++i) {
      int e = i*256 + tid;                 // [12 kc][64 o][8 j]
      int kc = e >> 9, o = (e >> 3) & 63, j = e & 7, k = kc*8 + j;
      float v = (k < 64) ? W0[o*C0 + 3 + k] : ((k < 67) ? W0[o*C0 + (k - 64)] : 0.f);
      Wt0c[e] = f2bf(v);
    }
  } else if (blk == 545) {
    for (int i = 0; i < 32; ++i) {
      int e = i*256 + tid;                 // [8 kc][128 n][8 j]
      int kc = e >> 10, n = (e >> 3) & 127, j = e & 7;
      Wt1c[e] = f2bf(W1[n*H0 + kc*8 + j]);
    }
  } else {
    int base = (blk - 546) * 4096;
    for (int i = 0; i < 16; ++i) {
      int e = base + i*256 + tid;          // [16 kc][256 n][8 j]
      int kc = e >> 11, n = (e >> 3) & 255, j = e & 7;
      Wt2c[e] = f2bf(W2[n*H1 + kc*8 + j]);
    }
  }
}

__global__ __launch_bounds__(256) void k_xyz_only(
    const float* __restrict__ xyz, const int* __restrict__ sidx, float* __restrict__ out_newxyz)
{
  int t0 = blockIdx.x*256 + threadIdx.x;
  int b = t0 >> 10;
  int s = sidx[t0];
  for (int k = 0; k < 3; ++k)
    out_newxyz[(size_t)t0*3 + k] = xyz[((size_t)(b*NN + s))*3 + k];
}

// ---------------------------------------------------------------------------
// L0: M=128, K=96 (12 chunks), Cout=64. 32x32 MFMA: wave w -> nt=w&1 (32ch),
// row tiles (w>>1)*64 + {0,32}. 12 MFMA/wave.
// ---------------------------------------------------------------------------
__global__ __launch_bounds__(256) void k_l0(
    const float* __restrict__ xyz, const int* __restrict__ sidx, const int* __restrict__ nidx,
    const u16* __restrict__ ptsT, const u16* __restrict__ Wt0c,
    u16* __restrict__ y0, float* __restrict__ stats)
{
  __shared__ u16 XLc[12*128*8];  // 24 KB
  __shared__ u16 W0c[12*64*8];   // 12 KB
  int tid = threadIdx.x;
  int m0 = blockIdx.x * 128;
  int b = m0 >> 15;

  for (int i = 0; i < 3; ++i)
    ((uint4*)W0c)[i*256 + tid] = ((const uint4*)Wt0c)[i*256 + tid];

  int pos = tid & 127, half = tid >> 7;
  int m = m0 + pos;
  int nb = nidx[m];
  {
    const uint4* prow = (const uint4*)(ptsT + ((size_t)(b*NN + nb))*CFF + half*32);
    uint4 h0 = prow[0], h1 = prow[1], h2 = prow[2], h3 = prow[3];
    *(uint4*)&XLc[((half*4+0)*128 + pos)*8] = h0;
    *(uint4*)&XLc[((half*4+1)*128 + pos)*8] = h1;
    *(uint4*)&XLc[((half*4+2)*128 + pos)*8] = h2;
    *(uint4*)&XLc[((half*4+3)*128 + pos)*8] = h3;
    if (half == 0) {
      int p = (m & 32767) >> 5;
      int sp = sidx[b*NPP + p];
      float r0 = xyz[((size_t)(b*NN+nb))*3+0] - xyz[((size_t)(b*NN+sp))*3+0];
      float r1 = xyz[((size_t)(b*NN+nb))*3+1] - xyz[((size_t)(b*NN+sp))*3+1];
      float r2 = xyz[((size_t)(b*NN+nb))*3+2] - xyz[((size_t)(b*NN+sp))*3+2];
      uint4 v = { pack2(r0, r1), pack2(r2, 0.f), 0u, 0u };
      *(uint4*)&XLc[(8*128 + pos)*8] = v;
    } else {
      uint4 z = {0u,0u,0u,0u};
      *(uint4*)&XLc[(9*128 + pos)*8]  = z;
      *(uint4*)&XLc[(10*128 + pos)*8] = z;
      *(uint4*)&XLc[(11*128 + pos)*8] = z;
    }
  }
  __syncthreads();

  int lane = tid & 63, wv = tid >> 6;
  int l31 = lane & 31, kh = lane >> 5;
  int nt = wv & 1, mtb = (wv >> 1) * 2;
  f32x16 acc[2];
  for (int mi = 0; mi < 2; ++mi) for (int r = 0; r < 16; ++r) acc[mi][r] = 0.f;

  for (int kt = 0; kt < 6; ++kt) {
    int ck = kt*2 + kh;
    short8 bfrag = *(const short8*)&W0c[(ck*64 + nt*32 + l31)*8];
    for (int mi = 0; mi < 2; ++mi) {
      short8 afrag = *(const short8*)&XLc[(ck*128 + (mtb+mi)*32 + l31)*8];
      acc[mi] = MFMA32(afrag, bfrag, acc[mi]);
    }
  }

  float s = 0.f, q = 0.f;
  for (int mi = 0; mi < 2; ++mi)
    for (int r = 0; r < 16; ++r) { float y = acc[mi][r]; s += y; q += y*y; }
  s += __shfl_xor(s, 32); q += __shfl_xor(q, 32);
  if (lane < 32) {
    int slot = blockIdx.x & 7;
    atomicAdd(&stats[slot*256 + nt*32 + lane], s);
    atomicAdd(&stats[2048 + slot*256 + nt*32 + lane], q);
  }
  for (int mi = 0; mi < 2; ++mi)
    for (int r = 0; r < 16; ++r) {
      int mm = (mtb+mi)*32 + (r&3) + 8*(r>>2) + 4*kh;
      y0[(size_t)(m0+mm)*H0 + nt*32 + l31] = f2bf(acc[mi][r]);
    }
}

// ---------------------------------------------------------------------------
// L1 stats: M=128, BN0+ReLU staged, GEMM1 (64->128) 32x32, stats1 only.
// wave w -> nt=w (32 ch), mt 0..3. 16 MFMA/wave.
// ---------------------------------------------------------------------------
__global__ __launch_bounds__(256) void k_l1s(
    const u16* __restrict__ y0, const u16* __restrict__ Wt1c,
    const float* __restrict__ g0, const float* __restrict__ e0,
    const float* __restrict__ stIn, float* __restrict__ stOut)
{
  __shared__ u16 X0c[8*128*8];   // 16 KB
  __shared__ u16 W1c[8*128*8];   // 16 KB
  __shared__ float scl0[64], sft0[64];
  int tid = threadIdx.x;
  int m0 = blockIdx.x * 128;

  if (tid < 64) {
    float s = 0.f, q = 0.f;
    for (int sl = 0; sl < 8; ++sl) { s += stIn[sl*256 + tid]; q += stIn[2048 + sl*256 + tid]; }
    float mu = s*INV_M, var = q*INV_M - mu*mu;
    float sc = g0[tid] * rsqrtf(var + BN_EPS);
    scl0[tid] = sc; sft0[tid] = e0[tid] - mu*sc;
  }
  for (int i = 0; i < 4; ++i)
    ((uint4*)W1c)[i*256 + tid] = ((const uint4*)Wt1c)[i*256 + tid];

  int pos = tid & 127, half = tid >> 7;
  {
    const u16* row = y0 + (size_t)(m0 + pos)*H0 + half*32;
    u16 hs[32];
    for (int t = 0; t < 4; ++t) *(uint4*)&hs[t*8] = ((const uint4*)row)[t];
    __syncthreads();   // scl0 ready
    u16 ob[32];
    for (int j = 0; j < 32; ++j) {
      int c = half*32 + j;
      ob[j] = f2bf(fmaxf(fmaf(scl0[c], bf2f(hs[j]), sft0[c]), 0.f));
    }
    for (int t = 0; t < 4; ++t)
      *(uint4*)&X0c[((half*4+t)*128 + pos)*8] = *(uint4*)&ob[t*8];
  }
  __syncthreads();

  int lane = tid & 63, wv = tid >> 6;
  int l31 = lane & 31, kh = lane >> 5;
  f32x16 acc[4];
  for (int mt = 0; mt < 4; ++mt) for (int r = 0; r < 16; ++r) acc[mt][r] = 0.f;

  for (int kt = 0; kt < 4; ++kt) {
    int ck = kt*2 + kh;
    short8 bfrag = *(const short8*)&W1c[(ck*128 + wv*32 + l31)*8];
    for (int mt = 0; mt < 4; ++mt) {
      short8 afrag = *(const short8*)&X0c[(ck*128 + mt*32 + l31)*8];
      acc[mt] = MFMA32(afrag, bfrag, acc[mt]);
    }
  }

  float s = 0.f, q = 0.f;
  for (int mt = 0; mt < 4; ++mt)
    for (int r = 0; r < 16; ++r) { float y = acc[mt][r]; s += y; q += y*y; }
  s += __shfl_xor(s, 32); q += __shfl_xor(q, 32);
  if (lane < 32) {
    int slot = blockIdx.x & 7;
    atomicAdd(&stOut[slot*256 + wv*32 + lane], s);
    atomicAdd(&stOut[2048 + slot*256 + wv*32 + lane], q);
  }
}

// ---------------------------------------------------------------------------
// L2 fused: M=64. GEMM1 (32x32, 8 MFMA/wave) -> BN1+ReLU scatter -> GEMM2
// (32x32, W2 in 32KB halves, 32 MFMA/wave) -> stats2 + per-32-row max/min.
// ---------------------------------------------------------------------------
__global__ __launch_bounds__(256) void k_l2f(
    const u16* __restrict__ y0, const u16* __restrict__ Wt1c, const u16* __restrict__ Wt2c,
    const float* __restrict__ g0, const float* __restrict__ e0,
    const float* __restrict__ g1, const float* __restrict__ e1,
    const float* __restrict__ st0, const float* __restrict__ st1, float* __restrict__ stOut,
    u16* __restrict__ mxp, u16* __restrict__ mnp)
{
  __shared__ u16 X1c[16*64*8];   // 16 KB [16 kc][64 m][8]
  __shared__ u16 UB[16384];      // 32 KB: ph1 X0c[0,4096)+W1c[4096,12288); ph2 W2 half
  __shared__ float scl0[64], sft0[64], scl1[128], sft1[128];
  int tid = threadIdx.x;
  int m0 = blockIdx.x * 64;

  if (tid < 64) {
    float s = 0.f, q = 0.f;
    for (int sl = 0; sl < 8; ++sl) { s += st0[sl*256 + tid]; q += st0[2048 + sl*256 + tid]; }
    float mu = s*INV_M, var = q*INV_M - mu*mu;
    float sc = g0[tid] * rsqrtf(var + BN_EPS);
    scl0[tid] = sc; sft0[tid] = e0[tid] - mu*sc;
  }
  if (tid < 128) {
    float s = 0.f, q = 0.f;
    for (int sl = 0; sl < 8; ++sl) { s += st1[sl*256 + tid]; q += st1[2048 + sl*256 + tid]; }
    float mu = s*INV_M, var = q*INV_M - mu*mu;
    float sc = g1[tid] * rsqrtf(var + BN_EPS);
    scl1[tid] = sc; sft1[tid] = e1[tid] - mu*sc;
  }
  u16* X0c = UB;          // [8 kc][64 m][8]
  u16* W1c = UB + 4096;   // [8 kc][128 n][8]
  for (int i = 0; i < 4; ++i)
    ((uint4*)W1c)[i*256 + tid] = ((const uint4*)Wt1c)[i*256 + tid];

  int pos = tid & 63, grp = tid >> 6;
  {
    const u16* row = y0 + (size_t)(m0 + pos)*H0 + grp*16;
    u16 hs[16];
    *(uint4*)&hs[0] = ((const uint4*)row)[0];
    *(uint4*)&hs[8] = ((const uint4*)row)[1];
    __syncthreads();   // scl0/scl1 ready
    u16 ob[16];
    for (int j = 0; j < 16; ++j) {
      int c = grp*16 + j;
      ob[j] = f2bf(fmaxf(fmaf(scl0[c], bf2f(hs[j]), sft0[c]), 0.f));
    }
    *(uint4*)&X0c[((2*grp)*64 + pos)*8]   = *(uint4*)&ob[0];
    *(uint4*)&X0c[((2*grp+1)*64 + pos)*8] = *(uint4*)&ob[8];
  }
  __syncthreads();

  int lane = tid & 63, wv = tid >> 6;
  int l31 = lane & 31, kh = lane >> 5;

  // ---- GEMM1: wave -> nt=wv (32 ch), mt 0..1 ----
  f32x16 acc1[2];
  for (int mt = 0; mt < 2; ++mt) for (int r = 0; r < 16; ++r) acc1[mt][r] = 0.f;
  for (int kt = 0; kt < 4; ++kt) {
    int ck = kt*2 + kh;
    short8 bfrag = *(const short8*)&W1c[(ck*128 + wv*32 + l31)*8];
    for (int mt = 0; mt < 2; ++mt) {
      short8 afrag = *(const short8*)&X0c[(ck*64 + mt*32 + l31)*8];
      acc1[mt] = MFMA32(afrag, bfrag, acc1[mt]);
    }
  }

  // ---- BN1+ReLU scatter C->A (channel fixed per lane) ----
  {
    int ch = wv*32 + l31;
    int cb = ch >> 3, cr = ch & 7;
    float sc1 = scl1[ch], sf1 = sft1[ch];
    for (int mt = 0; mt < 2; ++mt)
      for (int r = 0; r < 16; ++r) {
        int mm = mt*32 + (r&3) + 8*(r>>2) + 4*kh;
        X1c[(cb*64 + mm)*8 + cr] = f2bf(fmaxf(fmaf(sc1, acc1[mt][r], sf1), 0.f));
      }
  }
  __syncthreads();   // UB reads (GEMM1) + X1c writes complete

  // ---- GEMM2: wave -> ch wv*64 + nt*32, mt 0..1; W2 staged in halves ----
  f32x16 acc2[2][2];
  for (int nt = 0; nt < 2; ++nt) for (int mt = 0; mt < 2; ++mt)
    for (int r = 0; r < 16; ++r) acc2[nt][mt][r] = 0.f;

  for (int h = 0; h < 2; ++h) {
    for (int i = 0; i < 8; ++i)
      ((uint4*)UB)[i*256 + tid] = ((const uint4*)Wt2c)[h*2048 + i*256 + tid];
    __syncthreads();
    for (int k4 = 0; k4 < 4; ++k4) {
      int ckx = (h*4 + k4)*2 + kh;
      int ckw = k4*2 + kh;
      short8 a[2], bf_[2];
      for (int mt = 0; mt < 2; ++mt) a[mt]  = *(const short8*)&X1c[(ckx*64 + mt*32 + l31)*8];
      for (int nt = 0; nt < 2; ++nt) bf_[nt] = *(const short8*)&UB[(ckw*256 + wv*64 + nt*32 + l31)*8];
      for (int nt = 0; nt < 2; ++nt)
        for (int mt = 0; mt < 2; ++mt)
          acc2[nt][mt] = MFMA32(a[mt], bf_[nt], acc2[nt][mt]);
    }
    __syncthreads();
  }

  // ---- stats2 + max/min over NS (p-groups = row tiles mt) ----
  int slot = blockIdx.x & 7;
  for (int nt = 0; nt < 2; ++nt) {
    float s = 0.f, q = 0.f;
    float mx[2] = {-3.0e38f, -3.0e38f}, mn[2] = {3.0e38f, 3.0e38f};
    for (int mt = 0; mt < 2; ++mt)
      for (int r = 0; r < 16; ++r) {
        float y = acc2[nt][mt][r];
        s += y; q += y*y;
        mx[mt] = fmaxf(mx[mt], y); mn[mt] = fminf(mn[mt], y);
      }
    s += __shfl_xor(s, 32); q += __shfl_xor(q, 32);
    mx[0] = fmaxf(mx[0], __shfl_xor(mx[0], 32));
    mx[1] = fmaxf(mx[1], __shfl_xor(mx[1], 32));
    mn[0] = fminf(mn[0], __shfl_xor(mn[0], 32));
    mn[1] = fminf(mn[1], __shfl_xor(mn[1], 32));
    if (lane < 32) {
      int c = wv*64 + nt*32 + lane;
      atomicAdd(&stOut[slot*256 + c], s);
      atomicAdd(&stOut[2048 + slot*256 + c], q);
      for (int mt = 0; mt < 2; ++mt) {
        size_t pr = (size_t)blockIdx.x*2 + mt;
        mxp[pr*H2 + c] = f2bf(mx[mt]);
        mnp[pr*H2 + c] = f2bf(mn[mt]);
      }
    }
  }
}

// ---------------------------------------------------------------------------
__global__ __launch_bounds__(256) void k_final(
    const u16* __restrict__ mxp, const u16* __restrict__ mnp,
    const float* __restrict__ gma, const float* __restrict__ bta,
    const float* __restrict__ stIn, float* __restrict__ out_np)
{
  __shared__ float tmp[256][33];
  int tid = threadIdx.x;
  int b = blockIdx.x >> 5;
  int p0 = (blockIdx.x & 31) * 32;

  float s = 0.f, q = 0.f;
  for (int sl = 0; sl < 8; ++sl) { s += stIn[sl*256 + tid]; q += stIn[2048 + sl*256 + tid]; }
  float mu = s*INV_M, var = q*INV_M - mu*mu;
  float sc = gma[tid] * rsqrtf(var + BN_EPS);
  float sh = bta[tid] - mu*sc;

  for (int pp = 0; pp < 32; ++pp) {
    size_t base = ((size_t)(b*NPP + p0 + pp))*H2 + tid;
    float xv = bf2f(mxp[base]), nv = bf2f(mnp[base]);
    float v = (sc >= 0.f) ? fmaf(sc, xv, sh) : fmaf(sc, nv, sh);
    tmp[tid][pp] = fmaxf(v, 0.f);
  }
  __syncthreads();

  int pl = tid & 31, cg = tid >> 5;
  for (int cc = 0; cc < 32; ++cc) {
    int c = cc*8 + cg;
    out_np[((size_t)b*H2 + c)*NPP + p0 + pl] = tmp[c][pl];
  }
}

// ---------------------------------------------------------------------------
extern "C" void kernel_launch(void* const* d_in, const int* in_sizes, int n_in,
                              void* d_out, int out_size, void* d_ws, size_t ws_size,
                              hipStream_t stream)
{
  const float* xyz    = (const float*)d_in[0];
  const float* points = (const float*)d_in[1];
  const int*   sidx   = (const int*)d_in[2];
  const int*   nidx   = (const int*)d_in[3];
  const float* W0 = (const float*)d_in[4];
  const float* g0 = (const float*)d_in[6];
  const float* e0 = (const float*)d_in[7];
  const float* W1 = (const float*)d_in[8];
  const float* g1 = (const float*)d_in[10];
  const float* e1 = (const float*)d_in[11];
  const float* W2 = (const float*)d_in[12];
  const float* g2 = (const float*)d_in[14];
  const float* e2 = (const float*)d_in[15];

  float* out_xyz = (float*)d_out;
  float* out_np  = out_xyz + (size_t)BB*NPP*3;

  if (ws_size < (size_t)WS_NEED) {
    hipMemsetAsync(out_np, 0, (size_t)BB*H2*NPP*4, stream);
    k_xyz_only<<<32, 256, 0, stream>>>(xyz, sidx, out_xyz);
    return;
  }

  char* ws = (char*)d_ws;
  float* stats = (float*)(ws + 0);
  u16*   Wt0c  = (u16*)(ws + 49152);
  u16*   Wt1c  = (u16*)(ws + 61440);
  u16*   Wt2c  = (u16*)(ws + 77824);
  u16*   ptsT  = (u16*)(ws + 143360);
  u16*   y0    = (u16*)(ws + 4337664);
  u16*   mxp   = (u16*)(ws + 37892096);
  u16*   mnp   = (u16*)(ws + 42086400);

  hipMemsetAsync(stats, 0, 3*4096*sizeof(float), stream);
  k_setup<<<554, 256, 0, stream>>>(xyz, points, sidx, W0, W1, W2,
                                   ptsT, Wt0c, Wt1c, Wt2c, out_xyz);
  k_l0<<<MTOT/128, 256, 0, stream>>>(xyz, sidx, nidx, ptsT, Wt0c, y0, stats);
  k_l1s<<<MTOT/128, 256, 0, stream>>>(y0, Wt1c, g0, e0, stats, stats + 4096);
  k_l2f<<<MTOT/64, 256, 0, stream>>>(y0, Wt1c, Wt2c, g0, e0, g1, e1,
                                     stats, stats + 4096, stats + 8192, mxp, mnp);
  k_final<<<256, 256, 0, stream>>>(mxp, mnp, g2, e2, stats + 8192, out_np);
}